// Round 5
// baseline (1145.959 us; speedup 1.0000x reference)
//
#include <hip/hip_runtime.h>

#define GN    128
#define GBIG  1.0e5f
#define NITER 128

// Padded layout: x pitch 128, y and z padded to 130 with BIG boundary planes.
#define PPY     130
#define PITCH_Y 128
#define PITCH_Z (128 * 130)
#define PADDED_TOTAL (130 * 130 * 128)

// Persistent grid: tile 128 x 8 x 4 -> 16 x 32 logical blocks (512 total)
#define NBY  16
#define NBZ  32
#define NBLK (NBY * NBZ)

typedef float fx4 __attribute__((ext_vector_type(4)));
typedef int   ix4 __attribute__((ext_vector_type(4)));

// ---------------------------------------------------------------------------
// init: padded uA, uB, fP + inbox lines.
// inbox[b][slot 0..3] = value published by the {-y,+y,-z,+z} producer of b.
// Published value = ((xcc+1)<<16) | iter.  Missing producer => NITER (iter
// field satisfies any target; xcc field 0 is bypassed by the static missing
// check).  64B per block line.
// ---------------------------------------------------------------------------
__global__ __launch_bounds__(256) void eik_init(const float* __restrict__ u0,
                                                const float* __restrict__ f,
                                                float* __restrict__ uA,
                                                float* __restrict__ uB,
                                                float* __restrict__ fP,
                                                int* __restrict__ inbox) {
    const int i = blockIdx.x * 256 + threadIdx.x;
    if (i < NBLK * 16) {
        const int b = i >> 4, d = i & 15;
        const int ly = b & 15, lz = b >> 4;
        int v = 0;
        if ((d == 0 && ly == 0) || (d == 1 && ly == NBY - 1) ||
            (d == 2 && lz == 0) || (d == 3 && lz == NBZ - 1))
            v = NITER;
        inbox[i] = v;
    }
    if (i >= PADDED_TOTAL) return;
    const int x = i & 127;
    const int r = i >> 7;          // r = z*130 + y
    const int y = r % 130;
    const int z = r / 130;
    float uv = GBIG, fv = 0.0f;
    if (y >= 1 && y <= GN && z >= 1 && z <= GN) {
        const int src = ((z - 1) * GN + (y - 1)) * GN + x;
        uv = u0[src];
        fv = f[src];
    }
    uA[i] = uv;
    uB[i] = uv;
    fP[i] = fv;
}

__device__ __forceinline__ float eik_solve(float ax, float ay, float az,
                                           float fh, float uc) {
    const float a1 = fminf(fminf(ax, ay), az);
    const float a3 = fmaxf(fmaxf(ax, ay), az);
    const float a2 = fmaxf(fminf(fmaxf(ax, ay), az), fminf(ax, ay));
    const float x1 = a1 + fh;
    const float d12 = a1 - a2;
    const float disc2 = 2.0f * fh * fh - d12 * d12;
    const float x2 = 0.5f * (a1 + a2 + sqrtf(fmaxf(disc2, 0.0f)));
    const float s = a1 + a2 + a3;
    const float q = a1 * a1 + a2 * a2 + a3 * a3;
    const float disc3 = s * s - 3.0f * (q - fh * fh);
    const float x3 = (s + sqrtf(fmaxf(disc3, 0.0f))) * (1.0f / 3.0f);
    const float xv = (x1 <= a2) ? x1 : ((x2 <= a3) ? x2 : x3);
    return fminf(uc, xv);
}

// flag publish: ALWAYS device scope (sc1).  Flag lines have 4 writer blocks
// (possibly on different XCDs) — never mix cache scopes on a shared line.
__device__ __forceinline__ void pub(int* box, int byteOff, int val) {
    asm volatile("global_store_dword %0, %1, %2 sc1"
                 :: "v"(byteOff), "v"(val), "s"(box) : "memory");
}
// u-edge stores: fast (plain, L2-dirty; all consumers verified same-XCD) or
// slow (sc1, device scope).  u lines have a single writer block -> no mixed-
// writer-line hazard.
__device__ __forceinline__ void stF(float* D, int vo, fx4 v) {
    asm volatile("global_store_dwordx4 %0, %1, %2"
                 :: "v"(vo), "v"(v), "s"(D) : "memory");
}
__device__ __forceinline__ void stS(float* D, int vo, fx4 v) {
    asm volatile("global_store_dwordx4 %0, %1, %2 sc1"
                 :: "v"(vo), "v"(v), "s"(D) : "memory");
}

#define SOLVE_PLANE(nk, ck, xmk, xpk, ymk, ypk, zlo, zhi, fk)                  \
    nk.x = eik_solve(fminf(xmk, ck.y),  fminf(ymk.x, ypk.x),                   \
                     fminf(zlo.x, zhi.x), fk.x, ck.x);                         \
    nk.y = eik_solve(fminf(ck.x, ck.z), fminf(ymk.y, ypk.y),                   \
                     fminf(zlo.y, zhi.y), fk.y, ck.y);                         \
    nk.z = eik_solve(fminf(ck.y, ck.w), fminf(ymk.z, ypk.z),                   \
                     fminf(zlo.z, zhi.z), fk.z, ck.z);                         \
    nk.w = eik_solve(fminf(ck.z, xpk),  fminf(ymk.w, ypk.w),                   \
                     fminf(zlo.w, zhi.w), fk.w, ck.w);

// ---------------------------------------------------------------------------
// persistent kernel, plain launch (graph-capturable).  512 blocks, 2/CU by
// capacity (occupancy-checked).  Protocol identical to round 3/4 (flag>=i-1
// gates both RAW and WAR); new: XCD-verified fast path for u-halo traffic.
//
// XCD handshake: every flag value carries the producer's XCC_ID (+1) in the
// upper 16 bits.  Consumer-side: sc0 (L2) halo loads only when THIS round's
// flag proved the producer same-XCD.  Producer-side: plain (L2) edge stores
// only when ALL 4 neighbors' flags proved same-XCD ("allFast").  Any unknown
// or mismatch -> sc1 (L3, device scope).  Mixed pairings are safe: L2 is the
// XCD coherence point (all vmem from the XCD looks it up; dirty lines are
// honored by device-scope ops; sc1 stores write through it).
//
// Tile 128x8x4: u+f in registers; ONLY edge cells are ever stored (rows 0/7
// all planes; planes 0/3 all rows) — interior cells have no external reader.
// Logical blocks remapped so slab s = linear_bid%8 owns z-tiles [4s,4s+4):
// if the HW round-robins blocks over XCDs by %8, y- and intra-slab-z
// neighbors land same-XCD and go fast; if not, the handshake just leaves
// those interfaces on sc1 (correct either way).
// ---------------------------------------------------------------------------
__global__ __launch_bounds__(256, 4) void eik_persist(float* __restrict__ uA,
                                                      float* __restrict__ uB,
                                                      const float* __restrict__ fP,
                                                      float* __restrict__ out,
                                                      int* __restrict__ inbox) {
    const int lx = threadIdx.x;        // 0..31, 4 x-cells each
    const int ty = threadIdx.y;        // 0..7
    const int tid = ty * 32 + lx;

    // physical -> logical (XCD-slab) remap
    const int lin = blockIdx.y + 16 * blockIdx.z;  // 0..511
    const int t   = lin >> 3;                      // 0..63
    const int ly  = t & 15;                        // 0..15
    const int lz  = (lin & 7) * 4 + (t >> 4);      // 0..31

    const int gy  = ly * 8 + ty;       // 0..127
    const int gz0 = lz * 4;            // planes gz0..gz0+3
    const int x0  = lx * 4;

    int myxcc;
    asm("s_getreg_b32 %0, hwreg(HW_REG_XCC_ID)" : "=s"(myxcc));
    const int myx1 = (myxcc & 0xf) + 1;

    // per-cell act distances (exact active-set cull, as reference iteration)
    const int dxm = (x0 <= 64 && 64 <= x0 + 3) ? 0
                                               : min(abs(x0 - 64), abs(x0 + 3 - 64));
    const int dy = abs(gy - 64);
    const int d0 = dxm + dy + abs(gz0 - 64);
    const int d1 = dxm + dy + abs(gz0 + 1 - 64);
    const int d2 = dxm + dy + abs(gz0 + 2 - 64);
    const int d3 = dxm + dy + abs(gz0 + 3 - 64);
    const int dmin = min(min(d0, d1), min(d2, d3));

    // block/face distances
    const int ry0 = ly * 8, ry1 = ry0 + 7;
    const int dymin = (ry0 > 64) ? (ry0 - 64) : ((ry1 < 64) ? (64 - ry1) : 0);
    const int dzmin = (gz0 > 64) ? (gz0 - 64) : ((gz0 + 3 < 64) ? (64 - (gz0 + 3)) : 0);
    const int start = max(1, dymin + dzmin);
    const int dYm = abs(ry0 - 64) + dzmin;
    const int dYp = abs(ry1 - 64) + dzmin;
    const int dZm = abs(gz0 - 64) + dymin;
    const int dZp = abs(gz0 + 3 - 64) + dymin;

    const int idx = lz * NBY + ly;
    const int inbOff = idx * 64;
    const int pubYp = (idx + 1) * 64 + 0;
    const int pubYm = (idx - 1) * 64 + 4;
    const int pubZp = (idx + NBY) * 64 + 8;
    const int pubZm = (idx - NBY) * 64 + 12;

    if (tid == 0 && start > 1) {       // pre-publish u_{start-1}==u_0, with xcc
        const int pv = (myx1 << 16) | (start - 1);
        if (ly < NBY - 1) pub(inbox, pubYp, pv);
        if (ly > 0)       pub(inbox, pubYm, pv);
        if (lz < NBZ - 1) pub(inbox, pubZp, pv);
        if (lz > 0)       pub(inbox, pubZm, pv);
    }

    const int base0 = ((gz0 + 1) * PPY + (gy + 1)) * PITCH_Y + x0;
    const int vo0 = base0 * 4;
    const int vo1 = vo0 + PITCH_Z * 4;
    const int vo2 = vo1 + PITCH_Z * 4;
    const int vo3 = vo2 + PITCH_Z * 4;
    const int vozm = vo0 - PITCH_Z * 4;
    const int vozp = vo3 + PITCH_Z * 4;

    fx4 c0 = *(const fx4*)(uA + base0);
    fx4 c1 = *(const fx4*)(uA + base0 + PITCH_Z);
    fx4 c2 = *(const fx4*)(uA + base0 + 2 * PITCH_Z);
    fx4 c3 = *(const fx4*)(uA + base0 + 3 * PITCH_Z);
    const fx4 f0 = *(const fx4*)(fP + base0);
    const fx4 f1 = *(const fx4*)(fP + base0 + PITCH_Z);
    const fx4 f2 = *(const fx4*)(fP + base0 + 2 * PITCH_Z);
    const fx4 f3 = *(const fx4*)(fP + base0 + 3 * PITCH_Z);

    const bool yedge = (ty == 0) || (ty == 7);
    __shared__ int shAF;

    for (int i = start; i <= NITER; ++i) {
        // ---- wave 0 polls (sc1, flags always device scope); others park ----
        if (tid < 64) {
            const int tYm = (dYm <= i) ? i - 1 : -0x40000000;
            const int tYp = (dYp <= i) ? i - 1 : -0x40000000;
            const int tZm = (dZm <= i) ? i - 1 : -0x40000000;
            const int tZp = (dZp <= i) ? i - 1 : -0x40000000;
            ix4 v;
            for (;;) {
                asm volatile("global_load_dwordx4 %0, %1, %2 sc1\n\t"
                             "s_waitcnt vmcnt(0)"
                             : "=&v"(v) : "v"(inbOff), "s"(inbox) : "memory");
                if ((v.x & 0xffff) >= tYm && (v.y & 0xffff) >= tYp &&
                    (v.z & 0xffff) >= tZm && (v.w & 0xffff) >= tZp) break;
                __builtin_amdgcn_s_sleep(1);
            }
            if (tid == 0) {
                const int af =
                    ((ly == 0)       || (v.x >> 16) == myx1) &&
                    ((ly == NBY - 1) || (v.y >> 16) == myx1) &&
                    ((lz == 0)       || (v.z >> 16) == myx1) &&
                    ((lz == NBZ - 1) || (v.w >> 16) == myx1);
                shAF = af;
            }
        }
        __syncthreads();
        const int AF = shAF;

        // ---- x-neighbors via shuffles (unconditional) ----
        float xm0 = __shfl_up(c0.w, 1);   if (lx == 0)  xm0 = GBIG;
        float xp0 = __shfl_down(c0.x, 1); if (lx == 31) xp0 = GBIG;
        float xm1 = __shfl_up(c1.w, 1);   if (lx == 0)  xm1 = GBIG;
        float xp1 = __shfl_down(c1.x, 1); if (lx == 31) xp1 = GBIG;
        float xm2 = __shfl_up(c2.w, 1);   if (lx == 0)  xm2 = GBIG;
        float xp2 = __shfl_down(c2.x, 1); if (lx == 31) xp2 = GBIG;
        float xm3 = __shfl_up(c3.w, 1);   if (lx == 0)  xm3 = GBIG;
        float xp3 = __shfl_down(c3.x, 1); if (lx == 31) xp3 = GBIG;

        const bool run = (dmin <= i);
        fx4 n0, n1, n2, n3;
        if (run) {
            const float* S = (i & 1) ? uA : uB;
            fx4 ym0, yp0, ym1, yp1, ym2, yp2, ym3, yp3, zm, zp;
            if (AF) {  // all-verified same-XCD: L2-served loads (sc0 = L1 bypass)
                asm volatile(
                    "global_load_dwordx4 %0, %10, %16 offset:-512 sc0\n\t"
                    "global_load_dwordx4 %1, %10, %16 offset:512 sc0\n\t"
                    "global_load_dwordx4 %2, %11, %16 offset:-512 sc0\n\t"
                    "global_load_dwordx4 %3, %11, %16 offset:512 sc0\n\t"
                    "global_load_dwordx4 %4, %12, %16 offset:-512 sc0\n\t"
                    "global_load_dwordx4 %5, %12, %16 offset:512 sc0\n\t"
                    "global_load_dwordx4 %6, %13, %16 offset:-512 sc0\n\t"
                    "global_load_dwordx4 %7, %13, %16 offset:512 sc0\n\t"
                    "global_load_dwordx4 %8, %14, %16 sc0\n\t"
                    "global_load_dwordx4 %9, %15, %16 sc0\n\t"
                    "s_waitcnt vmcnt(0)"
                    : "=&v"(ym0), "=&v"(yp0), "=&v"(ym1), "=&v"(yp1),
                      "=&v"(ym2), "=&v"(yp2), "=&v"(ym3), "=&v"(yp3),
                      "=&v"(zm), "=&v"(zp)
                    : "v"(vo0), "v"(vo1), "v"(vo2), "v"(vo3),
                      "v"(vozm), "v"(vozp), "s"(S)
                    : "memory");
            } else {   // unknown/cross-XCD somewhere: device-scope loads
                asm volatile(
                    "global_load_dwordx4 %0, %10, %16 offset:-512 sc1\n\t"
                    "global_load_dwordx4 %1, %10, %16 offset:512 sc1\n\t"
                    "global_load_dwordx4 %2, %11, %16 offset:-512 sc1\n\t"
                    "global_load_dwordx4 %3, %11, %16 offset:512 sc1\n\t"
                    "global_load_dwordx4 %4, %12, %16 offset:-512 sc1\n\t"
                    "global_load_dwordx4 %5, %12, %16 offset:512 sc1\n\t"
                    "global_load_dwordx4 %6, %13, %16 offset:-512 sc1\n\t"
                    "global_load_dwordx4 %7, %13, %16 offset:512 sc1\n\t"
                    "global_load_dwordx4 %8, %14, %16 sc1\n\t"
                    "global_load_dwordx4 %9, %15, %16 sc1\n\t"
                    "s_waitcnt vmcnt(0)"
                    : "=&v"(ym0), "=&v"(yp0), "=&v"(ym1), "=&v"(yp1),
                      "=&v"(ym2), "=&v"(yp2), "=&v"(ym3), "=&v"(yp3),
                      "=&v"(zm), "=&v"(zp)
                    : "v"(vo0), "v"(vo1), "v"(vo2), "v"(vo3),
                      "v"(vozm), "v"(vozp), "s"(S)
                    : "memory");
            }

            SOLVE_PLANE(n0, c0, xm0, xp0, ym0, yp0, zm, c1, f0)
            SOLVE_PLANE(n1, c1, xm1, xp1, ym1, yp1, c0, c2, f1)
            SOLVE_PLANE(n2, c2, xm2, xp2, ym2, yp2, c1, c3, f2)
            SOLVE_PLANE(n3, c3, xm3, xp3, ym3, yp3, c2, zp, f3)
        }

        if (i < NITER) {
            float* D = (i & 1) ? uB : uA;
            if (run) {
                // only EDGE cells are stored: planes 0/3 (z-consumers) and,
                // for edge rows (ty 0/7), planes 1/2 too (y-consumers).
                if (AF) {
                    if (d0 <= i) { c0 = n0; stF(D, vo0, c0); }
                    if (d1 <= i) { c1 = n1; if (yedge) stF(D, vo1, c1); }
                    if (d2 <= i) { c2 = n2; if (yedge) stF(D, vo2, c2); }
                    if (d3 <= i) { c3 = n3; stF(D, vo3, c3); }
                } else {
                    if (d0 <= i) { c0 = n0; stS(D, vo0, c0); }
                    if (d1 <= i) { c1 = n1; if (yedge) stS(D, vo1, c1); }
                    if (d2 <= i) { c2 = n2; if (yedge) stS(D, vo2, c2); }
                    if (d3 <= i) { c3 = n3; stS(D, vo3, c3); }
                }
            }
            asm volatile("s_waitcnt vmcnt(0)" ::: "memory");   // per-wave drain
            const int pv = (myx1 << 16) | i;
            // early y-publish: the edge row is wholly owned by this wave
            if (tid == 0   && ly > 0)       pub(inbox, pubYm, pv);
            if (tid == 224 && ly < NBY - 1) pub(inbox, pubYp, pv);
            __syncthreads();                 // all waves' plane-edge stores done
            if (tid == 0) {
                if (lz > 0)       pub(inbox, pubZm, pv);
                if (lz < NBZ - 1) pub(inbox, pubZp, pv);
            }
        } else {
            if (run) {
                if (d0 <= i) c0 = n0;
                if (d1 <= i) c1 = n1;
                if (d2 <= i) c2 = n2;
                if (d3 <= i) c3 = n3;
            }
        }
    }

    // fused extract: compact 128^3 output straight from registers
    float* o = out + (gz0 * GN + gy) * GN + x0;
    *(fx4*)o = c0;
    *(fx4*)(o + GN * GN) = c1;
    *(fx4*)(o + 2 * GN * GN) = c2;
    *(fx4*)(o + 3 * GN * GN) = c3;
}

// ---------------------------------------------------------------------------
// fallback path (proven 128-launch structure) if occupancy check fails
// ---------------------------------------------------------------------------
__global__ __launch_bounds__(256) void eik_step(const float* __restrict__ uin,
                                                const float* __restrict__ fP,
                                                float* __restrict__ uout,
                                                int iter) {
    const int lx = threadIdx.x;
    const int gy = blockIdx.y * 8 + threadIdx.y;
    const int gz = blockIdx.z;
    const int x0 = 4 * lx;
    const int dxm = (x0 <= 64 && 64 <= x0 + 3)
                        ? 0
                        : min(abs(x0 - 64), abs(x0 + 3 - 64));
    const int d = dxm + abs(gy - 64) + abs(gz - 64);
    if (d > iter) return;

    const int y = gy + 1;
    const int z = gz + 1;
    const int base = (z * PPY + y) * PITCH_Y + x0;

    const float4 c  = *(const float4*)(uin + base);
    float xm_s = uin[base - 1];
    float xp_s = uin[base + 4];
    if (lx == 0)  xm_s = GBIG;
    if (lx == 31) xp_s = GBIG;
    const float4 ym = *(const float4*)(uin + base - PITCH_Y);
    const float4 yp = *(const float4*)(uin + base + PITCH_Y);
    const float4 zm = *(const float4*)(uin + base - PITCH_Z);
    const float4 zp = *(const float4*)(uin + base + PITCH_Z);
    const float4 f4 = *(const float4*)(fP + base);

    float4 res;
    res.x = eik_solve(fminf(xm_s, c.y), fminf(ym.x, yp.x), fminf(zm.x, zp.x), f4.x, c.x);
    res.y = eik_solve(fminf(c.x, c.z), fminf(ym.y, yp.y), fminf(zm.y, zp.y), f4.y, c.y);
    res.z = eik_solve(fminf(c.y, c.w), fminf(ym.z, yp.z), fminf(zm.z, zp.z), f4.z, c.z);
    res.w = eik_solve(fminf(c.z, xp_s), fminf(ym.w, yp.w), fminf(zm.w, zp.w), f4.w, c.w);

    *(float4*)(uout + base) = res;
}

__global__ __launch_bounds__(256) void eik_extract(const float* __restrict__ uf,
                                                   float* __restrict__ out) {
    const int j = blockIdx.x * 256 + threadIdx.x;
    const int x4 = j & 31;
    const int y  = (j >> 5) & 127;
    const int z  = j >> 12;
    const float4 v =
        *(const float4*)(uf + ((z + 1) * PPY + (y + 1)) * PITCH_Y + 4 * x4);
    *(float4*)(out + 4 * j) = v;
}

extern "C" void kernel_launch(void* const* d_in, const int* in_sizes, int n_in,
                              void* d_out, int out_size, void* d_ws, size_t ws_size,
                              hipStream_t stream) {
    const float* u0 = (const float*)d_in[0];
    const float* f  = (const float*)d_in[1];
    float* out = (float*)d_out;

    float* uA = (float*)d_ws;                    // 8.65 MB each
    float* uB = uA + PADDED_TOTAL;
    float* fP = uB + PADDED_TOTAL;
    int* inbox = (int*)(fP + PADDED_TOTAL);      // 32 KB padded inbox lines

    {
        const int nb = (PADDED_TOTAL + 255) / 256;
        eik_init<<<nb, 256, 0, stream>>>(u0, f, uA, uB, fP, inbox);
    }

    // Co-residency capacity check (host query, capture-safe, cached):
    // 512 blocks / 256 CUs -> need >= 2 blocks/CU resident.
    static int resident_ok = -1;
    if (resident_ok < 0) {
        int maxb = 0;
        hipError_t qe =
            hipOccupancyMaxActiveBlocksPerMultiprocessor(&maxb, eik_persist, 256, 0);
        resident_ok = (qe == hipSuccess && maxb >= 2) ? 1 : 0;
    }

    if (resident_ok) {
        eik_persist<<<dim3(1, NBY, NBZ), dim3(32, 8, 1), 0, stream>>>(uA, uB, fP,
                                                                      out, inbox);
        return;
    }

    // fallback: proven 128-launch ping-pong
    const dim3 block(32, 8, 1);
    const dim3 grid(1, 16, 128);
    for (int i = 1; i <= NITER; ++i) {
        const float* in = (i & 1) ? uA : uB;
        float* o        = (i & 1) ? uB : uA;
        eik_step<<<grid, block, 0, stream>>>(in, fP, o, i);
    }
    eik_extract<<<GN * GN * GN / 4 / 256, 256, 0, stream>>>(uA, out);
}

// Round 6
// 726.684 us; speedup vs baseline: 1.5770x; 1.5770x over previous
//
#include <hip/hip_runtime.h>

#define GN    128
#define GBIG  1.0e5f
#define NITER 128

// Padded layout: x pitch 128, y and z padded to 130 with BIG boundary planes.
#define PPY     130
#define PITCH_Y 128
#define PITCH_Z (128 * 130)
#define PADDED_TOTAL (130 * 130 * 128)

// Persistent grid: tile 128 x 8 x 2 -> 16 x 64 logical blocks (1024 total)
#define NBY  16
#define NBZ  64
#define NBLK (NBY * NBZ)

typedef float fx4 __attribute__((ext_vector_type(4)));
typedef int   ix4 __attribute__((ext_vector_type(4)));

// ---------------------------------------------------------------------------
// init: padded uA, uB, fP + inbox lines.
// inbox[b][0..3] = value from the {-y,+y,-z,+z} producer of b:
//   ((xcc+1)<<16) | iter.  Missing producer => NITER (iter satisfies any
//   target; xcc field 0 is excluded by static edge guards).  64B per block.
// ---------------------------------------------------------------------------
__global__ __launch_bounds__(256) void eik_init(const float* __restrict__ u0,
                                                const float* __restrict__ f,
                                                float* __restrict__ uA,
                                                float* __restrict__ uB,
                                                float* __restrict__ fP,
                                                int* __restrict__ inbox) {
    const int i = blockIdx.x * 256 + threadIdx.x;
    if (i < NBLK * 16) {
        const int b = i >> 4, d = i & 15;
        const int ly = b & 15, lz = b >> 4;
        int v = 0;
        if ((d == 0 && ly == 0) || (d == 1 && ly == NBY - 1) ||
            (d == 2 && lz == 0) || (d == 3 && lz == NBZ - 1))
            v = NITER;
        inbox[i] = v;
    }
    if (i >= PADDED_TOTAL) return;
    const int x = i & 127;
    const int r = i >> 7;          // r = z*130 + y
    const int y = r % 130;
    const int z = r / 130;
    float uv = GBIG, fv = 0.0f;
    if (y >= 1 && y <= GN && z >= 1 && z <= GN) {
        const int src = ((z - 1) * GN + (y - 1)) * GN + x;
        uv = u0[src];
        fv = f[src];
    }
    uA[i] = uv;
    uB[i] = uv;
    fP[i] = fv;
}

__device__ __forceinline__ float eik_solve(float ax, float ay, float az,
                                           float fh, float uc) {
    const float a1 = fminf(fminf(ax, ay), az);
    const float a3 = fmaxf(fmaxf(ax, ay), az);
    const float a2 = fmaxf(fminf(fmaxf(ax, ay), az), fminf(ax, ay));
    const float x1 = a1 + fh;
    const float d12 = a1 - a2;
    const float disc2 = 2.0f * fh * fh - d12 * d12;
    const float x2 = 0.5f * (a1 + a2 + sqrtf(fmaxf(disc2, 0.0f)));
    const float s = a1 + a2 + a3;
    const float q = a1 * a1 + a2 * a2 + a3 * a3;
    const float disc3 = s * s - 3.0f * (q - fh * fh);
    const float x3 = (s + sqrtf(fmaxf(disc3, 0.0f))) * (1.0f / 3.0f);
    const float xv = (x1 <= a2) ? x1 : ((x2 <= a3) ? x2 : x3);
    return fminf(uc, xv);
}

// flag publish: ALWAYS device scope (sc1) — flag lines have multiple writer
// blocks, possibly cross-XCD.
__device__ __forceinline__ void pub(int* box, int byteOff, int val) {
    asm volatile("global_store_dword %0, %1, %2 sc1"
                 :: "v"(byteOff), "v"(val), "s"(box) : "memory");
}
// u stores: fast (plain, stays dirty in the shared same-XCD L2) or slow
// (sc1 = device scope, write-through to L3).  Single writer per u line.
__device__ __forceinline__ void stF(float* D, int vo, fx4 v) {
    asm volatile("global_store_dwordx4 %0, %1, %2"
                 :: "v"(vo), "v"(v), "s"(D) : "memory");
}
__device__ __forceinline__ void stS(float* D, int vo, fx4 v) {
    asm volatile("global_store_dwordx4 %0, %1, %2 sc1"
                 :: "v"(vo), "v"(v), "s"(D) : "memory");
}

// ---------------------------------------------------------------------------
// persistent kernel, plain launch (graph-capturable).  1024 blocks, 4/CU by
// capacity (occupancy-checked).  Round-4 structure (proven 604us / absmax
// 0.5) + ONE new variable: XCD-verified fast path for u-halo traffic.
//
// Protocol: inbox slot >= i-1 gates both RAW and WAR (ping-pong buffers).
// Per-face direction culling as before.  ALL cells of both planes stored
// every active round (round-5's edge-only store was the staleness bug).
//
// XCD fast path: flags carry producer XCC_ID.  af = all four active
// neighbors same-XCD (xcc fields are constant once first published -> af is
// monotone 0->1; zero fields only occur for not-yet-active directions whose
// halo cells are still at init values in both buffers, so conservative slow
// mode is also correct).  af=1: sc0 halo loads (same-XCD L2 hit) + plain
// stores.  af=0: sc1 loads/stores (L3).  Cross-XCD consumers only ever read
// sc1-stored data (producer af accounts for all its consumers).
//
// z-slab remap: physical lin%8 -> slab owns lz in [8s, 8s+8).  Under the
// documented round-robin block->XCD dispatch, all y-interfaces and 7/8 of
// z-interfaces become same-XCD.  If the mapping differs, af simply stays 0
// and behavior is identical to round 4 (correct either way).
// ---------------------------------------------------------------------------
__global__ __launch_bounds__(256, 4) void eik_persist(float* __restrict__ uA,
                                                      float* __restrict__ uB,
                                                      const float* __restrict__ fP,
                                                      float* __restrict__ out,
                                                      int* __restrict__ inbox) {
    const int lx = threadIdx.x;        // 0..31, 4 x-cells each
    const int ty = threadIdx.y;        // 0..7
    const int tid = ty * 32 + lx;

    // physical -> logical (XCD-slab) remap
    const int lin  = blockIdx.y + 16 * blockIdx.z;  // 0..1023
    const int slab = lin & 7;
    const int t    = lin >> 3;                      // 0..127
    const int ly   = t & 15;                        // 0..15
    const int lz   = slab * 8 + (t >> 4);           // 0..63

    const int gy  = ly * 8 + ty;       // 0..127
    const int gz0 = lz * 2;            // plane pair gz0, gz0+1
    const int x0  = lx * 4;

    int myxcc;
    asm("s_getreg_b32 %0, hwreg(HW_REG_XCC_ID)" : "=s"(myxcc));
    const int myx1 = (myxcc & 0xf) + 1;

    // per-cell act distances (exact active-set cull)
    const int dxm = (x0 <= 64 && 64 <= x0 + 3) ? 0
                                               : min(abs(x0 - 64), abs(x0 + 3 - 64));
    const int dy = abs(gy - 64);
    const int d0 = dxm + dy + abs(gz0 - 64);
    const int d1 = dxm + dy + abs(gz0 + 1 - 64);
    const int dmin01 = min(d0, d1);

    // block/face distances
    const int ry0 = ly * 8, ry1 = ry0 + 7;
    const int dymin = (ry0 > 64) ? (ry0 - 64) : ((ry1 < 64) ? (64 - ry1) : 0);
    const int dzmin = min(abs(gz0 - 64), abs(gz0 + 1 - 64));
    const int start = max(1, dymin + dzmin);
    const int dYm = abs(ry0 - 64) + dzmin;       // face row y=0   (slot 0)
    const int dYp = abs(ry1 - 64) + dzmin;       // face row y=7   (slot 1)
    const int dZm = abs(gz0 - 64) + dymin;       // face plane 0   (slot 2)
    const int dZp = abs(gz0 + 1 - 64) + dymin;   // face plane 1   (slot 3)

    const int idx = lz * NBY + ly;
    const int inbOff = idx * 64;
    const int pubYp = (idx + 1) * 64 + 0;     // +y dependent, reads our row 7
    const int pubYm = (idx - 1) * 64 + 4;     // -y dependent, reads our row 0
    const int pubZp = (idx + NBY) * 64 + 8;   // +z dependent, reads our plane 1
    const int pubZm = (idx - NBY) * 64 + 12;  // -z dependent, reads our plane 0

    if (tid == 0 && start > 1) {   // pre-publish: u_{start-1} == u_0 here
        const int pv = (myx1 << 16) | (start - 1);
        if (ly < NBY - 1) pub(inbox, pubYp, pv);
        if (ly > 0)       pub(inbox, pubYm, pv);
        if (lz < NBZ - 1) pub(inbox, pubZp, pv);
        if (lz > 0)       pub(inbox, pubZm, pv);
    }

    const int base0 = ((gz0 + 1) * PPY + (gy + 1)) * PITCH_Y + x0;
    const int base1 = base0 + PITCH_Z;
    const int vo0  = base0 * 4;
    const int vo1  = base1 * 4;
    const int vozm = vo0 - PITCH_Z * 4;
    const int vozp = vo1 + PITCH_Z * 4;

    fx4 c0 = *(const fx4*)(uA + base0);
    fx4 c1 = *(const fx4*)(uA + base1);
    const fx4 f0 = *(const fx4*)(fP + base0);
    const fx4 f1 = *(const fx4*)(fP + base1);

    for (int i = start; i <= NITER; ++i) {
        // ---- single-load inbox spin (all threads), per-direction targets ----
        const int tYm = (dYm <= i) ? i - 1 : -0x40000000;
        const int tYp = (dYp <= i) ? i - 1 : -0x40000000;
        const int tZm = (dZm <= i) ? i - 1 : -0x40000000;
        const int tZp = (dZp <= i) ? i - 1 : -0x40000000;
        ix4 v;
        for (;;) {
            asm volatile("global_load_dwordx4 %0, %1, %2 sc1\n\t"
                         "s_waitcnt vmcnt(0)"
                         : "=&v"(v) : "v"(inbOff), "s"(inbox) : "memory");
            if ((v.x & 0xffff) >= tYm && (v.y & 0xffff) >= tYp &&
                (v.z & 0xffff) >= tZm && (v.w & 0xffff) >= tZp) break;
            __builtin_amdgcn_s_sleep(1);
        }
        // all-active-neighbors-same-XCD?  (fields constant once published)
        const bool af =
            ((ly == 0)       || (v.x >> 16) == myx1) &&
            ((ly == NBY - 1) || (v.y >> 16) == myx1) &&
            ((lz == 0)       || (v.z >> 16) == myx1) &&
            ((lz == NBZ - 1) || (v.w >> 16) == myx1);

        // ---- x-neighbors via shuffles (unconditional) ----
        float xm0 = __shfl_up(c0.w, 1);   if (lx == 0)  xm0 = GBIG;
        float xp0 = __shfl_down(c0.x, 1); if (lx == 31) xp0 = GBIG;
        float xm1 = __shfl_up(c1.w, 1);   if (lx == 0)  xm1 = GBIG;
        float xp1 = __shfl_down(c1.x, 1); if (lx == 31) xp1 = GBIG;

        const bool run = (dmin01 <= i);   // any of this thread's 8 cells live?
        fx4 n0, n1;
        if (run) {
            const float* S = (i & 1) ? uA : uB;
            fx4 ym0, yp0, ym1, yp1, zm, zp;
            if (af) {   // same-XCD: L2-served (sc0 = bypass L1 only)
                asm volatile(
                    "global_load_dwordx4 %0, %6, %10 offset:-512 sc0\n\t"
                    "global_load_dwordx4 %1, %6, %10 offset:512 sc0\n\t"
                    "global_load_dwordx4 %2, %7, %10 offset:-512 sc0\n\t"
                    "global_load_dwordx4 %3, %7, %10 offset:512 sc0\n\t"
                    "global_load_dwordx4 %4, %8, %10 sc0\n\t"
                    "global_load_dwordx4 %5, %9, %10 sc0\n\t"
                    "s_waitcnt vmcnt(0)"
                    : "=&v"(ym0), "=&v"(yp0), "=&v"(ym1), "=&v"(yp1),
                      "=&v"(zm), "=&v"(zp)
                    : "v"(vo0), "v"(vo1), "v"(vozm), "v"(vozp), "s"(S)
                    : "memory");
            } else {    // unknown / cross-XCD: device scope (L3)
                asm volatile(
                    "global_load_dwordx4 %0, %6, %10 offset:-512 sc1\n\t"
                    "global_load_dwordx4 %1, %6, %10 offset:512 sc1\n\t"
                    "global_load_dwordx4 %2, %7, %10 offset:-512 sc1\n\t"
                    "global_load_dwordx4 %3, %7, %10 offset:512 sc1\n\t"
                    "global_load_dwordx4 %4, %8, %10 sc1\n\t"
                    "global_load_dwordx4 %5, %9, %10 sc1\n\t"
                    "s_waitcnt vmcnt(0)"
                    : "=&v"(ym0), "=&v"(yp0), "=&v"(ym1), "=&v"(yp1),
                      "=&v"(zm), "=&v"(zp)
                    : "v"(vo0), "v"(vo1), "v"(vozm), "v"(vozp), "s"(S)
                    : "memory");
            }

            n0.x = eik_solve(fminf(xm0,  c0.y), fminf(ym0.x, yp0.x), fminf(zm.x, c1.x), f0.x, c0.x);
            n0.y = eik_solve(fminf(c0.x, c0.z), fminf(ym0.y, yp0.y), fminf(zm.y, c1.y), f0.y, c0.y);
            n0.z = eik_solve(fminf(c0.y, c0.w), fminf(ym0.z, yp0.z), fminf(zm.z, c1.z), f0.z, c0.z);
            n0.w = eik_solve(fminf(c0.z, xp0),  fminf(ym0.w, yp0.w), fminf(zm.w, c1.w), f0.w, c0.w);
            n1.x = eik_solve(fminf(xm1,  c1.y), fminf(ym1.x, yp1.x), fminf(c0.x, zp.x), f1.x, c1.x);
            n1.y = eik_solve(fminf(c1.x, c1.z), fminf(ym1.y, yp1.y), fminf(c0.y, zp.y), f1.y, c1.y);
            n1.z = eik_solve(fminf(c1.y, c1.w), fminf(ym1.z, yp1.z), fminf(c0.z, zp.z), f1.z, c1.z);
            n1.w = eik_solve(fminf(c1.z, xp1),  fminf(ym1.w, yp1.w), fminf(c0.w, zp.w), f1.w, c1.w);
        }

        if (i < NITER) {
            float* D = (i & 1) ? uB : uA;
            if (run) {
                if (af) {
                    if (d0 <= i) { c0 = n0; stF(D, vo0, c0); }
                    if (d1 <= i) { c1 = n1; stF(D, vo1, c1); }
                } else {
                    if (d0 <= i) { c0 = n0; stS(D, vo0, c0); }
                    if (d1 <= i) { c1 = n1; stS(D, vo1, c1); }
                }
            }
            asm volatile("s_waitcnt vmcnt(0)" ::: "memory");   // per-wave drain
            const int pv = (myx1 << 16) | i;
            // early y-publishes: the edge row is wholly owned by that wave
            if (tid == 0   && ly > 0)       pub(inbox, pubYm, pv);
            if (tid == 224 && ly < NBY - 1) pub(inbox, pubYp, pv);
            __syncthreads();                 // all waves' stores drained
            if (tid == 0) {
                if (lz > 0)       pub(inbox, pubZm, pv);
                if (lz < NBZ - 1) pub(inbox, pubZp, pv);
            }
        } else {
            if (run) {
                if (d0 <= i) c0 = n0;
                if (d1 <= i) c1 = n1;
            }
        }
    }

    // fused extract: compact 128^3 output straight from registers
    float* o = out + (gz0 * GN + gy) * GN + x0;
    *(fx4*)o = c0;
    *(fx4*)(o + GN * GN) = c1;
}

// ---------------------------------------------------------------------------
// fallback path (proven 128-launch structure) if occupancy check fails
// ---------------------------------------------------------------------------
__global__ __launch_bounds__(256) void eik_step(const float* __restrict__ uin,
                                                const float* __restrict__ fP,
                                                float* __restrict__ uout,
                                                int iter) {
    const int lx = threadIdx.x;
    const int gy = blockIdx.y * 8 + threadIdx.y;
    const int gz = blockIdx.z;
    const int x0 = 4 * lx;
    const int dxm = (x0 <= 64 && 64 <= x0 + 3)
                        ? 0
                        : min(abs(x0 - 64), abs(x0 + 3 - 64));
    const int d = dxm + abs(gy - 64) + abs(gz - 64);
    if (d > iter) return;

    const int y = gy + 1;
    const int z = gz + 1;
    const int base = (z * PPY + y) * PITCH_Y + x0;

    const float4 c  = *(const float4*)(uin + base);
    float xm_s = uin[base - 1];
    float xp_s = uin[base + 4];
    if (lx == 0)  xm_s = GBIG;
    if (lx == 31) xp_s = GBIG;
    const float4 ym = *(const float4*)(uin + base - PITCH_Y);
    const float4 yp = *(const float4*)(uin + base + PITCH_Y);
    const float4 zm = *(const float4*)(uin + base - PITCH_Z);
    const float4 zp = *(const float4*)(uin + base + PITCH_Z);
    const float4 f4 = *(const float4*)(fP + base);

    float4 res;
    res.x = eik_solve(fminf(xm_s, c.y), fminf(ym.x, yp.x), fminf(zm.x, zp.x), f4.x, c.x);
    res.y = eik_solve(fminf(c.x, c.z), fminf(ym.y, yp.y), fminf(zm.y, zp.y), f4.y, c.y);
    res.z = eik_solve(fminf(c.y, c.w), fminf(ym.z, yp.z), fminf(zm.z, zp.z), f4.z, c.z);
    res.w = eik_solve(fminf(c.z, xp_s), fminf(ym.w, yp.w), fminf(zm.w, zp.w), f4.w, c.w);

    *(float4*)(uout + base) = res;
}

__global__ __launch_bounds__(256) void eik_extract(const float* __restrict__ uf,
                                                   float* __restrict__ out) {
    const int j = blockIdx.x * 256 + threadIdx.x;
    const int x4 = j & 31;
    const int y  = (j >> 5) & 127;
    const int z  = j >> 12;
    const float4 v =
        *(const float4*)(uf + ((z + 1) * PPY + (y + 1)) * PITCH_Y + 4 * x4);
    *(float4*)(out + 4 * j) = v;
}

extern "C" void kernel_launch(void* const* d_in, const int* in_sizes, int n_in,
                              void* d_out, int out_size, void* d_ws, size_t ws_size,
                              hipStream_t stream) {
    const float* u0 = (const float*)d_in[0];
    const float* f  = (const float*)d_in[1];
    float* out = (float*)d_out;

    float* uA = (float*)d_ws;                    // 8.65 MB each
    float* uB = uA + PADDED_TOTAL;
    float* fP = uB + PADDED_TOTAL;
    int* inbox = (int*)(fP + PADDED_TOTAL);      // 64 KB padded inbox lines

    {
        const int nb = (PADDED_TOTAL + 255) / 256;
        eik_init<<<nb, 256, 0, stream>>>(u0, f, uA, uB, fP, inbox);
    }

    // Co-residency capacity check (host query, capture-safe, cached):
    // 1024 blocks / 256 CUs -> need >= 4 blocks/CU resident.
    static int resident_ok = -1;
    if (resident_ok < 0) {
        int maxb = 0;
        hipError_t qe =
            hipOccupancyMaxActiveBlocksPerMultiprocessor(&maxb, eik_persist, 256, 0);
        resident_ok = (qe == hipSuccess && maxb >= 4) ? 1 : 0;
    }

    if (resident_ok) {
        eik_persist<<<dim3(1, NBY, NBZ), dim3(32, 8, 1), 0, stream>>>(uA, uB, fP,
                                                                      out, inbox);
        return;
    }

    // fallback: proven 128-launch ping-pong
    const dim3 block(32, 8, 1);
    const dim3 grid(1, 16, 128);
    for (int i = 1; i <= NITER; ++i) {
        const float* in = (i & 1) ? uA : uB;
        float* o        = (i & 1) ? uB : uA;
        eik_step<<<grid, block, 0, stream>>>(in, fP, o, i);
    }
    eik_extract<<<GN * GN * GN / 4 / 256, 256, 0, stream>>>(uA, out);
}